// Round 1
// baseline (8439.404 us; speedup 1.0000x reference)
//
#include <hip/hip_runtime.h>
#include <hip/hip_fp16.h>
#include <math.h>

// Problem dims
#define B_  32
#define S_  256
#define I_  256
#define H_  512
#define N_  128
#define C_  64
#define O_  256
#define P_  268          // 4*C + 12
#define K_  832          // I + C + H
#define HB  (H_*B_)      // 16384
#define EPSX 1e-8f
#define NBLK 256

// Workspace layout (float offsets). Total 7,345,152 floats = 29.4 MB.
#define OFF_XT   0
#define SZ_XT    (S_*I_*B_)                 // x transposed [t][k][b]
#define OFF_HA   (OFF_XT + SZ_XT)
#define SZ_HA    ((S_+1)*H_*B_)             // h history [t][k][b]
#define OFF_RA   (OFF_HA + SZ_HA)
#define SZ_RA    ((S_+1)*C_*B_)             // r history [t][k][b]
#define OFF_CT   (OFF_RA + SZ_RA)
#define SZ_CT    (H_*B_)                    // (unused: c lives in registers)
#define OFF_M    (OFF_CT + SZ_CT)
#define SZ_M     (B_*N_*C_)                 // memory [b][n][c] (block-private)
#define OFF_WR   (OFF_M + SZ_M)
#define SZ_W     (B_*N_)                    // unused (layout stability)
#define OFF_WW   (OFF_WR + SZ_W)
#define OFF_BAR  (OFF_WW + SZ_W)
#define SZ_BAR   8192                       // arrive[256] + release[256], 64B-strided
#define OFF_WOT  (OFF_BAR + SZ_BAR)
#define SZ_WOT   ((H_+C_)*O_)               // W_out transposed [k][o]
#define OFF_WHH  (OFF_WOT + SZ_WOT)
#define SZ_WHH   ((P_*H_)/2)                // W_head as fp16 (137216 halves)

__device__ __forceinline__ float sigm(float x) { return 1.f / (1.f + expf(-x)); }
__device__ __forceinline__ float splus(float x) {
    return fmaxf(x, 0.f) + log1pf(expf(-fabsf(x)));  // stable softplus
}
__device__ __forceinline__ float wave_max(float v) {
    #pragma unroll
    for (int s = 1; s < 64; s <<= 1) v = fmaxf(v, __shfl_xor(v, s, 64));
    return v;
}
__device__ __forceinline__ float wave_sum(float v) {
    #pragma unroll
    for (int s = 1; s < 64; s <<= 1) v += __shfl_xor(v, s, 64);
    return v;
}

// Keep-alive: dependent FMA chain, defeats DCE via inline-asm tie.
__device__ __forceinline__ void junk16(float& s) {
    #pragma unroll
    for (int d = 0; d < 16; ++d) s = fmaf(s, 1.0000001f, 1e-9f);
    asm volatile("" : "+v"(s));
}

// HOT poll (single lane): dependent-FMA between agent-scope loads.
__device__ __forceinline__ void hotwait(unsigned* p, unsigned tgt) {
    float s = 1.f;
    while (__hip_atomic_load(p, __ATOMIC_RELAXED, __HIP_MEMORY_SCOPE_AGENT) < tgt)
        junk16(s);
}

// ---- contention-free grid barrier with ALL-LANE busy wait -----------------
// Round-10 post-mortem: VALUBusy 16% at "600 MHz-equivalent" step times —
// the chip downclocks because 99.8% of lanes idle in s_barrier during waits.
// Fix: non-master blocks spin ALL 512 lanes on an LDS mirror flag running
// dense FMA junk (full-chip FP32 activity -> DPM holds boost); tid0 forwards
// the global release line into the LDS flag.
//   arrive[bi]  @ bar[bi*16]        : writer=block bi, reader=master lane bi
//   release[bi] @ bar[4096 + bi*16] : writer=master lane bi, reader=block bi
__device__ __forceinline__ void gbar(unsigned* bar, volatile unsigned* ldsf,
                                     int bi, int tid, unsigned seq)
{
    __syncthreads();
    if (bi == NBLK - 1) {
        if (tid < NBLK - 1) hotwait(&bar[tid * 16], seq);
        else {
            float s = 1.f;  // non-polling master lanes stay hot too
            junk16(s);
        }
        __syncthreads();
        if (tid < NBLK)
            __hip_atomic_store(&bar[4096 + tid * 16], seq, __ATOMIC_RELAXED,
                               __HIP_MEMORY_SCOPE_AGENT);
        __syncthreads();
    } else {
        if (tid == 0) {
            asm volatile("s_waitcnt vmcnt(0) lgkmcnt(0)" ::: "memory");
            __hip_atomic_store(&bar[bi * 16], seq, __ATOMIC_RELAXED,
                               __HIP_MEMORY_SCOPE_AGENT);
        }
        // ALL lanes busy-spin on the LDS mirror; tid0 forwards global->LDS
        float s = (float)(tid + 1);
        for (;;) {
            if (*ldsf >= seq) break;
            if (tid == 0 &&
                __hip_atomic_load(&bar[4096 + bi * 16], __ATOMIC_RELAXED,
                                  __HIP_MEMORY_SCOPE_AGENT) >= seq)
                *ldsf = seq;
            junk16(s);
        }
        __syncthreads();   // reconverge (all lanes present -> cheap)
    }
}

// ---------------- prep: transpose x & W_out, fp16 W_head, init state -------
__global__ __launch_bounds__(256)
void prep_kernel(const float* __restrict__ x, const float* __restrict__ Wout,
                 const float* __restrict__ Whead, float* __restrict__ ws)
{
    int g = blockIdx.x * 256 + threadIdx.x;
    if (g < SZ_XT) {                       // xT[t][k][b] = x[b][t][k]
        int b = g & 31, k = (g >> 5) & 255, t = g >> 13;
        ws[OFF_XT + g] = x[b * (S_*I_) + t * I_ + k];
        return;
    }
    g -= SZ_XT;
    if (g < SZ_WOT) {                      // WoT[k][o] = W_out[o][k]
        int o = g & 255, k = g >> 8;
        ws[OFF_WOT + g] = Wout[o * (H_ + C_) + k];
        return;
    }
    g -= SZ_WOT;
    if (g < HB)      { ws[OFF_HA + g] = 0.f;   return; }   // h slot 0
    g -= HB;
    if (g < C_*B_)   { ws[OFF_RA + g] = 0.f;   return; }   // r slot 0
    g -= C_*B_;
    if (g < SZ_CT)   { ws[OFF_CT + g] = 0.f;   return; }   // (unused)
    g -= SZ_CT;
    if (g < SZ_M)    { ws[OFF_M  + g] = 0.01f; return; }   // M
    g -= SZ_M;
    if (g < 2*SZ_W)  { ws[OFF_WR + g] = 0.f;   return; }   // unused slots
    g -= 2*SZ_W;
    if (g < SZ_BAR)  { ws[OFF_BAR + g] = 0.f;  return; }   // barrier slots
    g -= SZ_BAR;
    if (g < P_ * H_) {                     // W_head -> fp16 copy
        ((__half*)(ws + OFF_WHH))[g] = __float2half(Whead[g]);
        return;
    }
}

// ---------------- persistent sequential loop -------------------------------
// 256 blocks x 512 threads, 1 block/CU, 2 padded-slot barriers per step with
// all-lane busy waits. Block bi: ug = bi>>1 owns units [4ug,4ug+4), bh = bi&1
// owns batches [16bh,16bh+16). Blocks 0..31 do ALL of phase B for batch bi;
// p, w_r, w_w in LDS; LSTM c in registers.
__global__ __launch_bounds__(512)
void ntm_loop(const float* __restrict__ Wih, const float* __restrict__ Whh,
              const float* __restrict__ bl,  const float* __restrict__ bhead,
              float* __restrict__ ws)
{
    float* xT  = ws + OFF_XT;
    float* hA  = ws + OFF_HA;
    float* rA  = ws + OFF_RA;
    float* Mem = ws + OFF_M;
    unsigned* bar = (unsigned*)(ws + OFF_BAR);
    const unsigned short* whH = (const unsigned short*)(ws + OFF_WHH);

    __shared__ float Wt[K_ * 18];     // gate rows transposed, stride 18
    __shared__ float p_lds[P_];
    __shared__ float sbuf[8];
    __shared__ float wtmp[128];
    __shared__ float wldsR[128];      // persistent w_r (blocks 0..31)
    __shared__ float wldsW[128];      // persistent w_w
    __shared__ float h_lds[H_];       // phase-B h staging
    __shared__ unsigned relf;         // LDS mirror of this block's release line

    const int tid = threadIdx.x;
    const int bi  = blockIdx.x;
    const int ug  = bi >> 1;
    const int bh  = bi & 1;

    if (tid == 0) relf = 0;

    // Load this block's 16 gate rows into LDS (once per launch).
    for (int idx = tid; idx < K_ * 16; idx += 512) {
        int rl = idx & 15, k = idx >> 4;
        int row = (rl & 3) * H_ + ug * 4 + (rl >> 2);
        float v = (k < I_ + C_) ? Wih[row * (I_ + C_) + k]
                                : Whh[row * H_ + (k - (I_ + C_))];
        Wt[k * 18 + rl] = v;
    }
    if (tid < N_) {                  // persistent addressing weights, w0 = e0
        wldsR[tid] = (tid == 0) ? 1.f : 0.f;
        wldsW[tid] = (tid == 0) ? 1.f : 0.f;
    }

    const int pair = tid >> 5;        // 0..15
    const int ks   = tid & 31;        // split-K lane
    const int rg   = pair >> 2;       // u_local 0..3
    const int bg   = pair & 3;        // batch quad 0..3
    const int b0   = bh * 16 + bg * 4;

    float cr[4] = {0.f, 0.f, 0.f, 0.f};   // LSTM c (ks==0 lanes only)
    unsigned seq = 0;

    for (int t = 0; t < S_; ++t) {
        // ------------- P1: gates GEMM + LSTM update -> h[t+1], c -------------
        {
            float acc[4][4] = {{0,0,0,0},{0,0,0,0},{0,0,0,0},{0,0,0,0}};
            const float* xs = xT + (size_t)t * I_ * B_;
            const float* rs = rA + (size_t)t * C_ * B_;
            const float* hs = hA + (size_t)t * HB;
            if (t == 0) __syncthreads();   // cover Wt / wlds / relf staging
            #pragma unroll
            for (int i = 0; i < 26; ++i) {
                const int k = ks + (i << 5);
                const float* ap;
                if (i < 8)       ap = xs + k * B_ + b0;
                else if (i < 10) ap = rs + (k - I_) * B_ + b0;
                else             ap = hs + (k - I_ - C_) * B_ + b0;
                const float4 a   = *(const float4*)ap;
                const float2 w01 = *(const float2*)&Wt[k * 18 + (rg << 2)];
                const float2 w23 = *(const float2*)&Wt[k * 18 + (rg << 2) + 2];
                const float wv[4] = {w01.x, w01.y, w23.x, w23.y};
                const float av[4] = {a.x, a.y, a.z, a.w};
                #pragma unroll
                for (int j = 0; j < 4; ++j)
                    #pragma unroll
                    for (int bb = 0; bb < 4; ++bb)
                        acc[j][bb] += wv[j] * av[bb];
            }
            // split-K butterfly over 32 lanes
            #pragma unroll
            for (int j = 0; j < 4; ++j)
                #pragma unroll
                for (int bb = 0; bb < 4; ++bb) {
                    float v = acc[j][bb];
                    v += __shfl_xor(v, 16, 64);
                    v += __shfl_xor(v, 8, 64);
                    v += __shfl_xor(v, 4, 64);
                    v += __shfl_xor(v, 2, 64);
                    v += __shfl_xor(v, 1, 64);
                    acc[j][bb] = v;
                }
            if (ks == 0) {
                const int unit = ug * 4 + rg;
                #pragma unroll
                for (int bb = 0; bb < 4; ++bb) {
                    const int b = b0 + bb;
                    float gi = acc[0][bb] + bl[unit];
                    float gf = acc[1][bb] + bl[H_ + unit];
                    float gg = acc[2][bb] + bl[2 * H_ + unit];
                    float go = acc[3][bb] + bl[3 * H_ + unit];
                    float cN = sigm(gf) * cr[bb] + sigm(gi) * tanhf(gg);
                    float hN = sigm(go) * tanhf(cN);
                    cr[bb] = cN;                       // c in registers
                    __hip_atomic_store(&hA[(size_t)(t + 1) * HB + unit * B_ + b],
                                       hN, __ATOMIC_RELAXED,
                                       __HIP_MEMORY_SCOPE_AGENT);
                }
            }
        }
        gbar(bar, &relf, bi, tid, ++seq);

        // ---- Phase B (blocks 0..31): head GEMM + addressing + write + read ----
        if (bi < B_) {
            const int b = bi;
            float* Mb = Mem + (size_t)b * N_ * C_;
            const float* hs = hA + (size_t)(t + 1) * HB;

            // stage h[:,b] into LDS (agent loads: read coherence point)
            h_lds[tid] = __hip_atomic_load(&hs[tid * B_ + b], __ATOMIC_RELAXED,
                                           __HIP_MEMORY_SCOPE_AGENT);
            __syncthreads();

            // head GEMM (fp16 weights): p = W_head @ h + b_head, 2 thr/row
            {
                const int sub  = tid & 1;        // k-half
                const int row0 = tid >> 1;       // 0..255
                const float* hb = &h_lds[sub * 256];
                #pragma unroll
                for (int rep = 0; rep < 2; ++rep) {
                    const int row = (rep == 0) ? row0
                                  : ((row0 < P_ - 256) ? row0 + 256 : -1);
                    if (row >= 0) {
                        const unsigned short* wrow = whH + row * H_ + sub * 256;
                        float acc = 0.f;
                        #pragma unroll 4
                        for (int k2 = 0; k2 < 256; k2 += 8) {
                            float4 raw = *(const float4*)&wrow[k2];  // 8 halves
                            const __half2* hp = (const __half2*)&raw;
                            float2 f0 = __half22float2(hp[0]);
                            float2 f1 = __half22float2(hp[1]);
                            float2 f2 = __half22float2(hp[2]);
                            float2 f3 = __half22float2(hp[3]);
                            acc += f0.x * hb[k2]     + f0.y * hb[k2 + 1]
                                 + f1.x * hb[k2 + 2] + f1.y * hb[k2 + 3]
                                 + f2.x * hb[k2 + 4] + f2.y * hb[k2 + 5]
                                 + f3.x * hb[k2 + 6] + f3.y * hb[k2 + 7];
                        }
                        acc += __shfl_xor(acc, 1, 64);
                        if (sub == 0) p_lds[row] = acc + bhead[row];
                    }
                }
            }
            __syncthreads();

            // addressing: pass 0 read head (params at 0), pass 1 write head (70)
            for (int pass = 0; pass < 2; ++pass) {
                const int o = pass ? 70 : 0;
                float z = 0.f, beta = 0.f, gate = 0.f, s0 = 0.f, s1 = 0.f,
                      s2 = 0.f, gamma = 1.f;
                if (tid < N_) {
                    beta  = splus(p_lds[o + 64]);
                    gate  = sigm(p_lds[o + 65]);
                    float sa = p_lds[o + 66], sbv = p_lds[o + 67], sc = p_lds[o + 68];
                    float sm3 = fmaxf(sa, fmaxf(sbv, sc));
                    float ea = __expf(sa - sm3), eb = __expf(sbv - sm3),
                          ec = __expf(sc - sm3);
                    float es3 = ea + eb + ec;
                    s0 = ea / es3; s1 = eb / es3; s2 = ec / es3;
                    gamma = 1.f + splus(p_lds[o + 69]);
                    float kk = 0.f;
                    #pragma unroll 8
                    for (int c = 0; c < C_; ++c) { float kv = p_lds[o + c]; kk += kv * kv; }
                    const float knorm = sqrtf(kk) + EPSX;
                    float dot = 0.f, mm = 0.f;
                    #pragma unroll
                    for (int c = 0; c < C_; c += 4) {
                        float4 m4 = *(const float4*)&Mb[tid * C_ + c];
                        dot += m4.x * p_lds[o + c]     + m4.y * p_lds[o + c + 1]
                             + m4.z * p_lds[o + c + 2] + m4.w * p_lds[o + c + 3];
                        mm  += m4.x * m4.x + m4.y * m4.y + m4.z * m4.z + m4.w * m4.w;
                    }
                    z = beta * (dot / ((sqrtf(mm) + EPSX) * knorm));
                }
                // softmax over n=128 via wave shuffles (waves 0,1 fully active)
                float zm = wave_max(z);
                if (tid < N_ && (tid & 63) == 0) sbuf[tid >> 6] = zm;
                __syncthreads();
                const float zmax = fmaxf(sbuf[0], sbuf[1]);
                float ev = (tid < N_) ? __expf(z - zmax) : 0.f;
                float es = wave_sum(ev);
                if (tid < N_ && (tid & 63) == 0) sbuf[2 + (tid >> 6)] = es;
                __syncthreads();
                const float esum = sbuf[2] + sbuf[3];
                if (tid < N_) {
                    float wc = ev / esum;
                    float wprev_v = pass ? wldsW[tid] : wldsR[tid];
                    wtmp[tid] = gate * wc + (1.f - gate) * wprev_v;
                }
                __syncthreads();
                float wp = 0.f;
                if (tid < N_) {
                    float wsft = s0 * wtmp[(tid + 1) & (N_-1)] + s1 * wtmp[tid]
                               + s2 * wtmp[(tid - 1) & (N_-1)];
                    wp = __powf(wsft + EPSX, gamma);
                }
                float ps = wave_sum(wp);
                if (tid < N_ && (tid & 63) == 0) sbuf[4 + (tid >> 6)] = ps;
                __syncthreads();
                const float psum = sbuf[4] + sbuf[5];
                if (tid < N_) {
                    float wn = wp / psum;
                    if (pass) wldsW[tid] = wn; else wldsR[tid] = wn;
                }
                __syncthreads();
            }

            // M = M*(1 - w_w e) + w_w a   (private)
            for (int idx = tid; idx < (N_ * C_) / 4; idx += 512) {
                const int n = idx >> 4;
                const int c = (idx & 15) << 2;
                const float wwn = wldsW[n];
                float4 m4 = *(float4*)&Mb[n * C_ + c];
                m4.x = m4.x * (1.f - wwn * sigm(p_lds[140 + c]))     + wwn * p_lds[204 + c];
                m4.y = m4.y * (1.f - wwn * sigm(p_lds[140 + c + 1])) + wwn * p_lds[204 + c + 1];
                m4.z = m4.z * (1.f - wwn * sigm(p_lds[140 + c + 2])) + wwn * p_lds[204 + c + 2];
                m4.w = m4.w * (1.f - wwn * sigm(p_lds[140 + c + 3])) + wwn * p_lds[204 + c + 3];
                *(float4*)&Mb[n * C_ + c] = m4;
            }
            __syncthreads();

            // r = w_r @ M_new  -> publish to L3
            {
                const int c = tid >> 3, ns = tid & 7;
                float acc = 0.f;
                #pragma unroll
                for (int i = 0; i < 16; ++i) {
                    const int n = ns + 8 * i;
                    acc += wldsR[n] * Mb[n * C_ + c];
                }
                acc += __shfl_xor(acc, 4, 64);
                acc += __shfl_xor(acc, 2, 64);
                acc += __shfl_xor(acc, 1, 64);
                if (ns == 0)
                    __hip_atomic_store(&rA[(size_t)(t + 1) * C_ * B_ + c * B_ + b],
                                       acc, __ATOMIC_RELAXED,
                                       __HIP_MEMORY_SCOPE_AGENT);
            }
        }
        gbar(bar, &relf, bi, tid, ++seq);
    }
}

// ---------------- final output GEMM ----------------
__global__ __launch_bounds__(256)
void out_kernel(const float* __restrict__ ws, const float* __restrict__ bout,
                float* __restrict__ out)
{
    __shared__ float actL[(H_ + C_) * 16];   // 36,864 B
    const float* hA  = ws + OFF_HA;
    const float* rA  = ws + OFF_RA;
    const float* WoT = ws + OFF_WOT;
    const int t   = blockIdx.x >> 1;
    const int bh  = blockIdx.x & 1;
    const int tid = threadIdx.x;

    for (int idx = tid; idx < (H_ + C_) * 16; idx += 256) {
        const int k = idx >> 4, bl2 = idx & 15, b = bh * 16 + bl2;
        float v = (k < H_) ? hA[(size_t)(t + 1) * HB + k * B_ + b]
                           : rA[(size_t)(t + 1) * C_ * B_ + (k - H_) * B_ + b];
        actL[k * 16 + bl2] = v;
    }
    __syncthreads();

    const int ot = tid & 63, bt = tid >> 6;
    const int o0 = ot * 4, bl0 = bt * 4;
    float acc[4][4] = {{0,0,0,0},{0,0,0,0},{0,0,0,0},{0,0,0,0}};
    for (int k = 0; k < H_ + C_; ++k) {
        const float4 w4 = *(const float4*)&WoT[k * O_ + o0];
        const float4 a4 = *(const float4*)&actL[k * 16 + bl0];
        const float wv[4] = {w4.x, w4.y, w4.z, w4.w};
        const float av[4] = {a4.x, a4.y, a4.z, a4.w};
        #pragma unroll
        for (int j = 0; j < 4; ++j)
            #pragma unroll
            for (int bb = 0; bb < 4; ++bb)
                acc[j][bb] += wv[j] * av[bb];
    }
    const float4 bo = *(const float4*)&bout[o0];
    #pragma unroll
    for (int bb = 0; bb < 4; ++bb) {
        const int b = bh * 16 + bl0 + bb;
        float4 res;
        res.x = acc[0][bb] + bo.x;
        res.y = acc[1][bb] + bo.y;
        res.z = acc[2][bb] + bo.z;
        res.w = acc[3][bb] + bo.w;
        *(float4*)&out[((size_t)b * S_ + t) * O_ + o0] = res;
    }
}

extern "C" void kernel_launch(void* const* d_in, const int* in_sizes, int n_in,
                              void* d_out, int out_size, void* d_ws, size_t ws_size,
                              hipStream_t stream)
{
    const float* x    = (const float*)d_in[0];
    const float* Wih  = (const float*)d_in[1];
    const float* Whh  = (const float*)d_in[2];
    const float* bl   = (const float*)d_in[3];
    const float* Whd  = (const float*)d_in[4];
    const float* bhd  = (const float*)d_in[5];
    const float* Wout = (const float*)d_in[6];
    const float* bout = (const float*)d_in[7];
    float* ws  = (float*)d_ws;    // needs 29.4 MB
    float* out = (float*)d_out;

    prep_kernel<<<10529, 256, 0, stream>>>(x, Wout, Whd, ws);

    void* args[] = { (void*)&Wih, (void*)&Whh, (void*)&bl,
                     (void*)&bhd, (void*)&ws };
    (void)hipLaunchCooperativeKernel((void*)ntm_loop, dim3(256), dim3(512), args, 0, stream);

    out_kernel<<<512, 256, 0, stream>>>(ws, bout, out);
}

// Round 2
// 7902.360 us; speedup vs baseline: 1.0680x; 1.0680x over previous
//
#include <hip/hip_runtime.h>
#include <hip/hip_fp16.h>
#include <math.h>

// Problem dims
#define B_  32
#define S_  256
#define I_  256
#define H_  512
#define N_  128
#define C_  64
#define O_  256
#define P_  268          // 4*C + 12
#define K_  832          // I + C + H
#define HB  (H_*B_)      // 16384
#define EPSX 1e-8f
#define NBLK 160         // 32 PB blocks + 128 gate blocks
#define NPB  32

// Workspace layout (float offsets) — unchanged from baseline.
#define OFF_XT   0
#define SZ_XT    (S_*I_*B_)
#define OFF_HA   (OFF_XT + SZ_XT)
#define SZ_HA    ((S_+1)*H_*B_)
#define OFF_RA   (OFF_HA + SZ_HA)
#define SZ_RA    ((S_+1)*C_*B_)
#define OFF_CT   (OFF_RA + SZ_RA)
#define SZ_CT    (H_*B_)
#define OFF_M    (OFF_CT + SZ_CT)
#define SZ_M     (B_*N_*C_)
#define OFF_WR   (OFF_M + SZ_M)
#define SZ_W     (B_*N_)
#define OFF_WW   (OFF_WR + SZ_W)
#define OFF_BAR  (OFF_WW + SZ_W)
#define SZ_BAR   8192
#define OFF_WOT  (OFF_BAR + SZ_BAR)
#define SZ_WOT   ((H_+C_)*O_)
#define OFF_WHH  (OFF_WOT + SZ_WOT)
#define SZ_WHH   ((P_*H_)/2)

__device__ __forceinline__ float sigm(float x) { return 1.f / (1.f + expf(-x)); }
__device__ __forceinline__ float splus(float x) {
    return fmaxf(x, 0.f) + log1pf(expf(-fabsf(x)));
}
__device__ __forceinline__ float wave_max(float v) {
    #pragma unroll
    for (int s = 1; s < 64; s <<= 1) v = fmaxf(v, __shfl_xor(v, s, 64));
    return v;
}
__device__ __forceinline__ float wave_sum(float v) {
    #pragma unroll
    for (int s = 1; s < 64; s <<= 1) v += __shfl_xor(v, s, 64);
    return v;
}

__device__ __forceinline__ void junk16(float& s) {
    #pragma unroll
    for (int d = 0; d < 16; ++d) s = fmaf(s, 1.0000001f, 1e-9f);
    asm volatile("" : "+v"(s));
}

__device__ __forceinline__ void hotwait(unsigned* p, unsigned tgt) {
    float s = 1.f;
    while (__hip_atomic_load(p, __ATOMIC_RELAXED, __HIP_MEMORY_SCOPE_AGENT) < tgt)
        junk16(s);
}

// Contention-free grid barrier, all-lane busy wait (proven in baseline).
__device__ __forceinline__ void gbar(unsigned* bar, volatile unsigned* ldsf,
                                     int bi, int tid, unsigned seq)
{
    __syncthreads();
    if (bi == NBLK - 1) {
        if (tid < NBLK - 1) hotwait(&bar[tid * 16], seq);
        else {
            float s = 1.f;
            junk16(s);
        }
        __syncthreads();
        if (tid < NBLK)
            __hip_atomic_store(&bar[4096 + tid * 16], seq, __ATOMIC_RELAXED,
                               __HIP_MEMORY_SCOPE_AGENT);
        __syncthreads();
    } else {
        if (tid == 0) {
            asm volatile("s_waitcnt vmcnt(0) lgkmcnt(0)" ::: "memory");
            __hip_atomic_store(&bar[bi * 16], seq, __ATOMIC_RELAXED,
                               __HIP_MEMORY_SCOPE_AGENT);
        }
        float s = (float)(tid + 1);
        for (;;) {
            if (*ldsf >= seq) break;
            if (tid == 0 &&
                __hip_atomic_load(&bar[4096 + bi * 16], __ATOMIC_RELAXED,
                                  __HIP_MEMORY_SCOPE_AGENT) >= seq)
                *ldsf = seq;
            junk16(s);
        }
        __syncthreads();
    }
}

// ---------------- prep: transpose x & W_out, fp16 W_head, init state -------
__global__ __launch_bounds__(256)
void prep_kernel(const float* __restrict__ x, const float* __restrict__ Wout,
                 const float* __restrict__ Whead, float* __restrict__ ws)
{
    int g = blockIdx.x * 256 + threadIdx.x;
    if (g < SZ_XT) {
        int b = g & 31, k = (g >> 5) & 255, t = g >> 13;
        ws[OFF_XT + g] = x[b * (S_*I_) + t * I_ + k];
        return;
    }
    g -= SZ_XT;
    if (g < SZ_WOT) {
        int o = g & 255, k = g >> 8;
        ws[OFF_WOT + g] = Wout[o * (H_ + C_) + k];
        return;
    }
    g -= SZ_WOT;
    if (g < HB)      { ws[OFF_HA + g] = 0.f;   return; }
    g -= HB;
    if (g < C_*B_)   { ws[OFF_RA + g] = 0.f;   return; }
    g -= C_*B_;
    if (g < SZ_CT)   { ws[OFF_CT + g] = 0.f;   return; }
    g -= SZ_CT;
    if (g < SZ_M)    { ws[OFF_M  + g] = 0.01f; return; }
    g -= SZ_M;
    if (g < 2*SZ_W)  { ws[OFF_WR + g] = 0.f;   return; }
    g -= 2*SZ_W;
    if (g < SZ_BAR)  { ws[OFF_BAR + g] = 0.f;  return; }
    g -= SZ_BAR;
    if (g < P_ * H_) {
        ((__half*)(ws + OFF_WHH))[g] = __float2half(Whead[g]);
        return;
    }
}

// GEMM inner step: one k-column, 4 gate rows x 8 batches into acc.
#define GEMM_STEP(khat, ap) {                                             \
    const float4 a0 = *(const float4*)(ap);                               \
    const float4 a1 = *(const float4*)((ap) + 4);                         \
    const float2 w01 = *(const float2*)&Wt[(khat) * 18 + (rg << 2)];      \
    const float2 w23 = *(const float2*)&Wt[(khat) * 18 + (rg << 2) + 2];  \
    const float wv[4] = {w01.x, w01.y, w23.x, w23.y};                     \
    const float av[8] = {a0.x, a0.y, a0.z, a0.w, a1.x, a1.y, a1.z, a1.w}; \
    _Pragma("unroll")                                                     \
    for (int j = 0; j < 4; ++j)                                           \
        _Pragma("unroll")                                                 \
        for (int bb = 0; bb < 8; ++bb)                                    \
            acc[j][bb] += wv[j] * av[bb]; }

// ---------------- persistent sequential loop -------------------------------
// 160 blocks x 512 threads. Blocks 0..31: phase-B (NTM head) for batch bi.
// Blocks 32..159: gate block gi=bi-32 owns units [4gi,4gi+4) for ALL 32
// batches. Per step:
//   W-A (gate blocks): fold r_t into register partial, butterfly, LSTM
//        activation, publish h[t+1].           (r-dependent tail only)
//   bar1
//   W-B: PB blocks do full phase B (h[t+1] -> r[t+1], M, w).
//        gate blocks concurrently compute the x+h partial of gates(t+1).
//   bar2
__global__ __launch_bounds__(512)
void ntm_loop(const float* __restrict__ Wih, const float* __restrict__ Whh,
              const float* __restrict__ bl,  const float* __restrict__ bhead,
              float* __restrict__ ws)
{
    float* xT  = ws + OFF_XT;
    float* hA  = ws + OFF_HA;
    float* rA  = ws + OFF_RA;
    float* Mem = ws + OFF_M;
    unsigned* bar = (unsigned*)(ws + OFF_BAR);
    const unsigned short* whH = (const unsigned short*)(ws + OFF_WHH);

    __shared__ float Wt[K_ * 18];     // gate blocks: weights (PB blocks: unused)
    __shared__ float p_lds[P_];
    __shared__ float wldsR[128];
    __shared__ float wldsW[128];
    __shared__ float h_lds[H_];       // PB: h staging; aliased wtmp/sbuf later
    __shared__ unsigned relf;

    const int tid  = threadIdx.x;
    const int bi   = blockIdx.x;
    const bool isPB = (bi < NPB);
    const int gi   = bi - NPB;        // gate block index 0..127

    if (tid == 0) relf = 0;

    if (!isPB) {
        // Stage this gate block's 16 rows (4 units x 4 gates), stride 18.
        for (int idx = tid; idx < K_ * 16; idx += 512) {
            int rl = idx & 15, k = idx >> 4;
            int row = (rl & 3) * H_ + gi * 4 + (rl >> 2);
            float v = (k < I_ + C_) ? Wih[row * (I_ + C_) + k]
                                    : Whh[row * H_ + (k - (I_ + C_))];
            Wt[k * 18 + rl] = v;
        }
    } else if (tid < N_) {
        wldsR[tid] = (tid == 0) ? 1.f : 0.f;
        wldsW[tid] = (tid == 0) ? 1.f : 0.f;
    }
    __syncthreads();   // staging visible before first use

    const int pair = tid >> 5;        // 0..15
    const int ks   = tid & 31;        // split-K lane
    const int rg   = pair >> 2;       // unit_local 0..3
    const int bg   = pair & 3;        // batch octet 0..3
    const int b0   = bg * 8;          // 8 batches per pair

    float acc[4][8];
    float cr[8] = {0,0,0,0,0,0,0,0};  // LSTM c (ks==0 lanes)
    float bI = 0, bF = 0, bG = 0, bO = 0;
    if (!isPB && ks == 0) {
        const int unit = gi * 4 + rg;
        bI = bl[unit];        bF = bl[H_ + unit];
        bG = bl[2*H_ + unit]; bO = bl[3*H_ + unit];
    }

    // ---- pre-loop: partial(0) over x[0] and h[0](=0) -----------------------
    if (!isPB) {
        #pragma unroll
        for (int j = 0; j < 4; ++j)
            #pragma unroll
            for (int bb = 0; bb < 8; ++bb) acc[j][bb] = 0.f;
        {
            const float* xs = xT;             // t = 0
            const float* hs = hA;             // slot 0 (zeros)
            #pragma unroll
            for (int i = 0; i < 8; ++i) {
                const int k = ks + (i << 5);
                GEMM_STEP(k, xs + k * B_ + b0);
            }
            #pragma unroll
            for (int i = 0; i < 16; ++i) {
                const int k = ks + (i << 5);          // 0..511
                GEMM_STEP(320 + k, hs + k * B_ + b0);
            }
        }
    }

    unsigned seq = 0;

    for (int t = 0; t < S_; ++t) {
        // ---------------- W-A: fold r_t, butterfly, activation --------------
        if (!isPB) {
            const float* rs = rA + (size_t)t * C_ * B_;
            #pragma unroll
            for (int i = 0; i < 2; ++i) {
                const int k = ks + (i << 5);          // 0..63
                GEMM_STEP(256 + k, rs + k * B_ + b0);
            }
            #pragma unroll
            for (int j = 0; j < 4; ++j)
                #pragma unroll
                for (int bb = 0; bb < 8; ++bb) {
                    float v = acc[j][bb];
                    v += __shfl_xor(v, 16, 64);
                    v += __shfl_xor(v, 8, 64);
                    v += __shfl_xor(v, 4, 64);
                    v += __shfl_xor(v, 2, 64);
                    v += __shfl_xor(v, 1, 64);
                    acc[j][bb] = v;
                }
            if (ks == 0) {
                const int unit = gi * 4 + rg;
                #pragma unroll
                for (int bb = 0; bb < 8; ++bb) {
                    const int b = b0 + bb;
                    float gI = acc[0][bb] + bI;
                    float gF = acc[1][bb] + bF;
                    float gG = acc[2][bb] + bG;
                    float gO = acc[3][bb] + bO;
                    float cN = sigm(gF) * cr[bb] + sigm(gI) * tanhf(gG);
                    float hN = sigm(gO) * tanhf(cN);
                    cr[bb] = cN;
                    __hip_atomic_store(&hA[(size_t)(t + 1) * HB + unit * B_ + b],
                                       hN, __ATOMIC_RELAXED,
                                       __HIP_MEMORY_SCOPE_AGENT);
                }
            }
        }
        gbar(bar, &relf, bi, tid, ++seq);

        // ---------------- W-B ------------------------------------------------
        if (isPB) {
            // ------- Phase B for batch bi -------
            const int b = bi;
            float* Mb = Mem + (size_t)b * N_ * C_;
            const float* hs = hA + (size_t)(t + 1) * HB;

            h_lds[tid] = __hip_atomic_load(&hs[tid * B_ + b], __ATOMIC_RELAXED,
                                           __HIP_MEMORY_SCOPE_AGENT);
            __syncthreads();

            // head GEMM (fp16 weights): p = W_head @ h + b_head, 2 thr/row
            {
                const int sub  = tid & 1;
                const int row0 = tid >> 1;
                const float* hb = &h_lds[sub * 256];
                #pragma unroll
                for (int rep = 0; rep < 2; ++rep) {
                    const int row = (rep == 0) ? row0
                                  : ((row0 < P_ - 256) ? row0 + 256 : -1);
                    if (row >= 0) {
                        const unsigned short* wrow = whH + row * H_ + sub * 256;
                        float acch = 0.f;
                        #pragma unroll 4
                        for (int k2 = 0; k2 < 256; k2 += 8) {
                            float4 raw = *(const float4*)&wrow[k2];
                            const __half2* hp = (const __half2*)&raw;
                            float2 f0 = __half22float2(hp[0]);
                            float2 f1 = __half22float2(hp[1]);
                            float2 f2 = __half22float2(hp[2]);
                            float2 f3 = __half22float2(hp[3]);
                            acch += f0.x * hb[k2]     + f0.y * hb[k2 + 1]
                                  + f1.x * hb[k2 + 2] + f1.y * hb[k2 + 3]
                                  + f2.x * hb[k2 + 4] + f2.y * hb[k2 + 5]
                                  + f3.x * hb[k2 + 6] + f3.y * hb[k2 + 7];
                        }
                        acch += __shfl_xor(acch, 1, 64);
                        if (sub == 0) p_lds[row] = acch + bhead[row];
                    }
                }
            }
            __syncthreads();

            // ------- dual-pass addressing: grp0=read head, grp1=write head --
            // h_lds is dead now; alias scratch into it.
            {
                float* wtmpA = h_lds;            // [2][128]
                float* sbufA = h_lds + 256;      // [16]
                const int grp = (tid >> 7) & 1;
                const int l   = tid & 127;
                const bool act256 = (tid < 256);
                const int o = grp ? 70 : 0;
                const int widx = (tid >> 6) & 1; // wave-within-group

                float z = 0.f, gate = 0.f, s0 = 0.f, s1 = 0.f, s2 = 0.f,
                      gamma = 1.f;
                if (act256) {
                    float beta = splus(p_lds[o + 64]);
                    gate = sigm(p_lds[o + 65]);
                    float sa = p_lds[o + 66], sbv = p_lds[o + 67],
                          sc = p_lds[o + 68];
                    float sm3 = fmaxf(sa, fmaxf(sbv, sc));
                    float ea = __expf(sa - sm3), eb = __expf(sbv - sm3),
                          ec = __expf(sc - sm3);
                    float es3 = ea + eb + ec;
                    s0 = ea / es3; s1 = eb / es3; s2 = ec / es3;
                    gamma = 1.f + splus(p_lds[o + 69]);
                    float kk = 0.f;
                    #pragma unroll 8
                    for (int c = 0; c < C_; ++c) {
                        float kv = p_lds[o + c]; kk += kv * kv;
                    }
                    const float knorm = sqrtf(kk) + EPSX;
                    float dot = 0.f, mm = 0.f;
                    #pragma unroll
                    for (int c = 0; c < C_; c += 4) {
                        float4 m4 = *(const float4*)&Mb[l * C_ + c];
                        dot += m4.x * p_lds[o + c]     + m4.y * p_lds[o + c + 1]
                             + m4.z * p_lds[o + c + 2] + m4.w * p_lds[o + c + 3];
                        mm  += m4.x * m4.x + m4.y * m4.y + m4.z * m4.z
                             + m4.w * m4.w;
                    }
                    z = beta * (dot / ((sqrtf(mm) + EPSX) * knorm));
                }
                float zm = wave_max(z);
                if (act256 && (tid & 63) == 0) sbufA[grp * 8 + widx] = zm;
                __syncthreads();
                const float zmax = fmaxf(sbufA[grp * 8], sbufA[grp * 8 + 1]);
                float ev = act256 ? __expf(z - zmax) : 0.f;
                float es = wave_sum(ev);
                if (act256 && (tid & 63) == 0) sbufA[grp * 8 + 2 + widx] = es;
                __syncthreads();
                const float esum = sbufA[grp * 8 + 2] + sbufA[grp * 8 + 3];
                if (act256) {
                    float wc = ev / esum;
                    float wprev = grp ? wldsW[l] : wldsR[l];
                    wtmpA[grp * 128 + l] = gate * wc + (1.f - gate) * wprev;
                }
                __syncthreads();
                float wp = 0.f;
                if (act256) {
                    float wsft = s0 * wtmpA[grp * 128 + ((l + 1) & 127)]
                               + s1 * wtmpA[grp * 128 + l]
                               + s2 * wtmpA[grp * 128 + ((l - 1) & 127)];
                    wp = __powf(wsft + EPSX, gamma);
                }
                float ps = wave_sum(wp);
                if (act256 && (tid & 63) == 0) sbufA[grp * 8 + 4 + widx] = ps;
                __syncthreads();
                const float psum = sbufA[grp * 8 + 4] + sbufA[grp * 8 + 5];
                if (act256) {
                    float wn = wp / psum;
                    if (grp) wldsW[l] = wn; else wldsR[l] = wn;
                }
                __syncthreads();
            }

            // M = M*(1 - w_w e) + w_w a
            for (int idx = tid; idx < (N_ * C_) / 4; idx += 512) {
                const int n = idx >> 4;
                const int c = (idx & 15) << 2;
                const float wwn = wldsW[n];
                float4 m4 = *(float4*)&Mb[n * C_ + c];
                m4.x = m4.x * (1.f - wwn * sigm(p_lds[140 + c]))     + wwn * p_lds[204 + c];
                m4.y = m4.y * (1.f - wwn * sigm(p_lds[140 + c + 1])) + wwn * p_lds[204 + c + 1];
                m4.z = m4.z * (1.f - wwn * sigm(p_lds[140 + c + 2])) + wwn * p_lds[204 + c + 2];
                m4.w = m4.w * (1.f - wwn * sigm(p_lds[140 + c + 3])) + wwn * p_lds[204 + c + 3];
                *(float4*)&Mb[n * C_ + c] = m4;
            }
            __syncthreads();

            // r = w_r @ M_new  -> publish
            {
                const int c = tid >> 3, ns = tid & 7;
                float accr = 0.f;
                #pragma unroll
                for (int i = 0; i < 16; ++i) {
                    const int n = ns + 8 * i;
                    accr += wldsR[n] * Mb[n * C_ + c];
                }
                accr += __shfl_xor(accr, 4, 64);
                accr += __shfl_xor(accr, 2, 64);
                accr += __shfl_xor(accr, 1, 64);
                if (ns == 0)
                    __hip_atomic_store(&rA[(size_t)(t + 1) * C_ * B_ + c * B_ + b],
                                       accr, __ATOMIC_RELAXED,
                                       __HIP_MEMORY_SCOPE_AGENT);
            }
        } else {
            // ------- gate blocks: partial(t+1) over x[t+1], h[t+1] -------
            #pragma unroll
            for (int j = 0; j < 4; ++j)
                #pragma unroll
                for (int bb = 0; bb < 8; ++bb) acc[j][bb] = 0.f;
            if (t + 1 < S_) {
                const float* xs = xT + (size_t)(t + 1) * I_ * B_;
                const float* hs = hA + (size_t)(t + 1) * HB;
                #pragma unroll
                for (int i = 0; i < 8; ++i) {
                    const int k = ks + (i << 5);
                    GEMM_STEP(k, xs + k * B_ + b0);
                }
                #pragma unroll
                for (int i = 0; i < 16; ++i) {
                    const int k = ks + (i << 5);
                    GEMM_STEP(320 + k, hs + k * B_ + b0);
                }
            }
        }
        gbar(bar, &relf, bi, tid, ++seq);
    }
}

// ---------------- final output GEMM ----------------
__global__ __launch_bounds__(256)
void out_kernel(const float* __restrict__ ws, const float* __restrict__ bout,
                float* __restrict__ out)
{
    __shared__ float actL[(H_ + C_) * 16];
    const float* hA  = ws + OFF_HA;
    const float* rA  = ws + OFF_RA;
    const float* WoT = ws + OFF_WOT;
    const int t   = blockIdx.x >> 1;
    const int bh  = blockIdx.x & 1;
    const int tid = threadIdx.x;

    for (int idx = tid; idx < (H_ + C_) * 16; idx += 256) {
        const int k = idx >> 4, bl2 = idx & 15, b = bh * 16 + bl2;
        float v = (k < H_) ? hA[(size_t)(t + 1) * HB + k * B_ + b]
                           : rA[(size_t)(t + 1) * C_ * B_ + (k - H_) * B_ + b];
        actL[k * 16 + bl2] = v;
    }
    __syncthreads();

    const int ot = tid & 63, bt = tid >> 6;
    const int o0 = ot * 4, bl0 = bt * 4;
    float acc[4][4] = {{0,0,0,0},{0,0,0,0},{0,0,0,0},{0,0,0,0}};
    for (int k = 0; k < H_ + C_; ++k) {
        const float4 w4 = *(const float4*)&WoT[k * O_ + o0];
        const float4 a4 = *(const float4*)&actL[k * 16 + bl0];
        const float wv[4] = {w4.x, w4.y, w4.z, w4.w};
        const float av[4] = {a4.x, a4.y, a4.z, a4.w};
        #pragma unroll
        for (int j = 0; j < 4; ++j)
            #pragma unroll
            for (int bb = 0; bb < 4; ++bb)
                acc[j][bb] += wv[j] * av[bb];
    }
    const float4 bo = *(const float4*)&bout[o0];
    #pragma unroll
    for (int bb = 0; bb < 4; ++bb) {
        const int b = bh * 16 + bl0 + bb;
        float4 res;
        res.x = acc[0][bb] + bo.x;
        res.y = acc[1][bb] + bo.y;
        res.z = acc[2][bb] + bo.z;
        res.w = acc[3][bb] + bo.w;
        *(float4*)&out[((size_t)b * S_ + t) * O_ + o0] = res;
    }
}

extern "C" void kernel_launch(void* const* d_in, const int* in_sizes, int n_in,
                              void* d_out, int out_size, void* d_ws, size_t ws_size,
                              hipStream_t stream)
{
    const float* x    = (const float*)d_in[0];
    const float* Wih  = (const float*)d_in[1];
    const float* Whh  = (const float*)d_in[2];
    const float* bl   = (const float*)d_in[3];
    const float* Whd  = (const float*)d_in[4];
    const float* bhd  = (const float*)d_in[5];
    const float* Wout = (const float*)d_in[6];
    const float* bout = (const float*)d_in[7];
    float* ws  = (float*)d_ws;
    float* out = (float*)d_out;

    prep_kernel<<<10529, 256, 0, stream>>>(x, Wout, Whd, ws);

    void* args[] = { (void*)&Wih, (void*)&Whh, (void*)&bl,
                     (void*)&bhd, (void*)&ws };
    (void)hipLaunchCooperativeKernel((void*)ntm_loop, dim3(NBLK), dim3(512), args, 0, stream);

    out_kernel<<<512, 256, 0, stream>>>(ws, bout, out);
}

// Round 3
// 7114.614 us; speedup vs baseline: 1.1862x; 1.1107x over previous
//
#include <hip/hip_runtime.h>
#include <hip/hip_fp16.h>
#include <math.h>

// Problem dims
#define B_  32
#define S_  256
#define I_  256
#define H_  512
#define N_  128
#define C_  64
#define O_  256
#define P_  268          // 4*C + 12
#define K_  832          // I + C + H
#define HB  (H_*B_)      // 16384
#define EPSX 1e-8f
#define NBLK 160         // 32 PB blocks + 128 gate blocks
#define NPB  32
#define NGATE 128

// Workspace layout (float offsets) — unchanged from baseline.
#define OFF_XT   0
#define SZ_XT    (S_*I_*B_)
#define OFF_HA   (OFF_XT + SZ_XT)
#define SZ_HA    ((S_+1)*H_*B_)
#define OFF_RA   (OFF_HA + SZ_HA)
#define SZ_RA    ((S_+1)*C_*B_)
#define OFF_CT   (OFF_RA + SZ_RA)
#define SZ_CT    (H_*B_)
#define OFF_M    (OFF_CT + SZ_CT)
#define SZ_M     (B_*N_*C_)
#define OFF_WR   (OFF_M + SZ_M)
#define SZ_W     (B_*N_)
#define OFF_WW   (OFF_WR + SZ_W)
#define OFF_BAR  (OFF_WW + SZ_W)
#define SZ_BAR   8192                       // flag_h[128] @ +0, flag_r[32] @ +4096 (stride 16)
#define OFF_WOT  (OFF_BAR + SZ_BAR)
#define SZ_WOT   ((H_+C_)*O_)
#define OFF_WHH  (OFF_WOT + SZ_WOT)
#define SZ_WHH   ((P_*H_)/2)

__device__ __forceinline__ float sigm(float x) { return 1.f / (1.f + expf(-x)); }
__device__ __forceinline__ float splus(float x) {
    return fmaxf(x, 0.f) + log1pf(expf(-fabsf(x)));
}
__device__ __forceinline__ float wave_max(float v) {
    #pragma unroll
    for (int s = 1; s < 64; s <<= 1) v = fmaxf(v, __shfl_xor(v, s, 64));
    return v;
}
__device__ __forceinline__ float wave_sum(float v) {
    #pragma unroll
    for (int s = 1; s < 64; s <<= 1) v += __shfl_xor(v, s, 64);
    return v;
}

// Keep-alive dependent FMA chain (holds clocks up during spin; proven).
__device__ __forceinline__ void junk16(float& s) {
    #pragma unroll
    for (int d = 0; d < 16; ++d) s = fmaf(s, 1.0000001f, 1e-9f);
    asm volatile("" : "+v"(s));
}

// ---- point-to-point flag wait ---------------------------------------------
// Waves 0,1 poll one flag per lane (clamped when nf<128); wave-wide __all
// detects completion; lane 0 mirrors into LDS. Waves 2..7 hot-spin on the
// LDS mirror (all lanes stay VALU-busy -> DPM holds boost). One-hop sync:
// producer store -> consumer observe, no master round-trip.
__device__ __forceinline__ void wait_flags(unsigned* flags, int nf, unsigned tgt,
                                           volatile unsigned* ldsp, int tid)
{
    const int wv = tid >> 6, ln = tid & 63;
    if (wv < 2) {
        int idx = wv * 64 + ln;
        if (idx >= nf) idx = nf - 1;
        unsigned* p = &flags[idx * 16];
        float s = 1.f;
        for (;;) {
            unsigned v = __hip_atomic_load(p, __ATOMIC_RELAXED,
                                           __HIP_MEMORY_SCOPE_AGENT);
            if (__all((int)(v >= tgt))) break;
            junk16(s);
        }
        if (ln == 0) ldsp[wv] = tgt;
    } else {
        float s = (float)(tid + 1);
        while (ldsp[0] < tgt || ldsp[1] < tgt) junk16(s);
    }
    __syncthreads();
}

// ---------------- prep: transpose x & W_out, fp16 W_head, init state -------
__global__ __launch_bounds__(256)
void prep_kernel(const float* __restrict__ x, const float* __restrict__ Wout,
                 const float* __restrict__ Whead, float* __restrict__ ws)
{
    int g = blockIdx.x * 256 + threadIdx.x;
    if (g < SZ_XT) {
        int b = g & 31, k = (g >> 5) & 255, t = g >> 13;
        ws[OFF_XT + g] = x[b * (S_*I_) + t * I_ + k];
        return;
    }
    g -= SZ_XT;
    if (g < SZ_WOT) {
        int o = g & 255, k = g >> 8;
        ws[OFF_WOT + g] = Wout[o * (H_ + C_) + k];
        return;
    }
    g -= SZ_WOT;
    if (g < HB)      { ws[OFF_HA + g] = 0.f;   return; }
    g -= HB;
    if (g < C_*B_)   { ws[OFF_RA + g] = 0.f;   return; }
    g -= C_*B_;
    if (g < SZ_CT)   { ws[OFF_CT + g] = 0.f;   return; }
    g -= SZ_CT;
    if (g < SZ_M)    { ws[OFF_M  + g] = 0.01f; return; }
    g -= SZ_M;
    if (g < 2*SZ_W)  { ws[OFF_WR + g] = 0.f;   return; }
    g -= 2*SZ_W;
    if (g < SZ_BAR)  { ws[OFF_BAR + g] = 0.f;  return; }
    g -= SZ_BAR;
    if (g < P_ * H_) {
        ((__half*)(ws + OFF_WHH))[g] = __float2half(Whead[g]);
        return;
    }
}

// GEMM inner step: one k-column, 4 gate rows x 8 batches into acc.
#define GEMM_STEP(khat, ap) {                                             \
    const float4 a0 = *(const float4*)(ap);                               \
    const float4 a1 = *(const float4*)((ap) + 4);                         \
    const float2 w01 = *(const float2*)&Wt[(khat) * 18 + (rg << 2)];      \
    const float2 w23 = *(const float2*)&Wt[(khat) * 18 + (rg << 2) + 2];  \
    const float wv[4] = {w01.x, w01.y, w23.x, w23.y};                     \
    const float av[8] = {a0.x, a0.y, a0.z, a0.w, a1.x, a1.y, a1.z, a1.w}; \
    _Pragma("unroll")                                                     \
    for (int j = 0; j < 4; ++j)                                           \
        _Pragma("unroll")                                                 \
        for (int bb = 0; bb < 8; ++bb)                                    \
            acc[j][bb] += wv[j] * av[bb]; }

// ---------------- persistent sequential loop -------------------------------
// 160 blocks x 512 threads, point-to-point flag sync (no grid barrier).
// Per step t:
//   gates: wait flag_r>=t  -> fold r[t], activate, publish h[t+1], flag_h=t+1
//          -> wait flag_h>=t+1 (all 128) -> x/h partial for t+1
//   PB:    wait flag_h>=t+1 (all 128) -> phase B -> publish r[t+1], flag_r=t+1
// Each block waits ONCE per step on its true dependency only.
__global__ __launch_bounds__(512)
void ntm_loop(const float* __restrict__ Wih, const float* __restrict__ Whh,
              const float* __restrict__ bl,  const float* __restrict__ bhead,
              float* __restrict__ ws)
{
    float* xT  = ws + OFF_XT;
    float* hA  = ws + OFF_HA;
    float* rA  = ws + OFF_RA;
    float* Mem = ws + OFF_M;
    unsigned* bar = (unsigned*)(ws + OFF_BAR);
    unsigned* flag_h = bar;            // [128] stride 16
    unsigned* flag_r = bar + 4096;     // [32]  stride 16
    const unsigned short* whH = (const unsigned short*)(ws + OFF_WHH);

    __shared__ float Wt[K_ * 18];     // gate blocks: weights (PB: unused)
    __shared__ float p_lds[P_];
    __shared__ float wldsR[128];
    __shared__ float wldsW[128];
    __shared__ float h_lds[H_];       // PB: h staging; aliased scratch later
    __shared__ unsigned syncf[4];     // LDS flag mirrors

    const int tid  = threadIdx.x;
    const int bi   = blockIdx.x;
    const bool isPB = (bi < NPB);
    const int gi   = bi - NPB;        // gate block index 0..127

    if (tid < 4) syncf[tid] = 0;

    if (!isPB) {
        for (int idx = tid; idx < K_ * 16; idx += 512) {
            int rl = idx & 15, k = idx >> 4;
            int row = (rl & 3) * H_ + gi * 4 + (rl >> 2);
            float v = (k < I_ + C_) ? Wih[row * (I_ + C_) + k]
                                    : Whh[row * H_ + (k - (I_ + C_))];
            Wt[k * 18 + rl] = v;
        }
    } else if (tid < N_) {
        wldsR[tid] = (tid == 0) ? 1.f : 0.f;
        wldsW[tid] = (tid == 0) ? 1.f : 0.f;
    }
    __syncthreads();   // staging + syncf visible

    const int pair = tid >> 5;        // 0..15
    const int ks   = tid & 31;        // split-K lane
    const int rg   = pair >> 2;       // unit_local 0..3
    const int bg   = pair & 3;        // batch octet 0..3
    const int b0   = bg * 8;          // 8 batches per pair

    float acc[4][8];
    float cr[8] = {0,0,0,0,0,0,0,0};  // LSTM c (ks==0 lanes)
    float bI = 0, bF = 0, bG = 0, bO = 0;
    if (!isPB && ks == 0) {
        const int unit = gi * 4 + rg;
        bI = bl[unit];        bF = bl[H_ + unit];
        bG = bl[2*H_ + unit]; bO = bl[3*H_ + unit];
    }

    if (!isPB) {
        // pre-loop partial(0): x[0] + h[0](=0)
        #pragma unroll
        for (int j = 0; j < 4; ++j)
            #pragma unroll
            for (int bb = 0; bb < 8; ++bb) acc[j][bb] = 0.f;
        const float* xs = xT;
        const float* hs = hA;
        #pragma unroll
        for (int i = 0; i < 8; ++i) {
            const int k = ks + (i << 5);
            GEMM_STEP(k, xs + k * B_ + b0);
        }
        #pragma unroll
        for (int i = 0; i < 16; ++i) {
            const int k = ks + (i << 5);
            GEMM_STEP(320 + k, hs + k * B_ + b0);
        }

        // ================= gate block main loop =================
        for (int t = 0; t < S_; ++t) {
            // wait r[t] (32 PB flags); t=0 trivially satisfied
            wait_flags(flag_r, NPB, (unsigned)t, &syncf[0], tid);

            const float* rs = rA + (size_t)t * C_ * B_;
            #pragma unroll
            for (int i = 0; i < 2; ++i) {
                const int k = ks + (i << 5);
                GEMM_STEP(256 + k, rs + k * B_ + b0);
            }
            #pragma unroll
            for (int j = 0; j < 4; ++j)
                #pragma unroll
                for (int bb = 0; bb < 8; ++bb) {
                    float v = acc[j][bb];
                    v += __shfl_xor(v, 16, 64);
                    v += __shfl_xor(v, 8, 64);
                    v += __shfl_xor(v, 4, 64);
                    v += __shfl_xor(v, 2, 64);
                    v += __shfl_xor(v, 1, 64);
                    acc[j][bb] = v;
                }
            if (ks == 0) {
                const int unit = gi * 4 + rg;
                #pragma unroll
                for (int bb = 0; bb < 8; ++bb) {
                    const int b = b0 + bb;
                    float gI = acc[0][bb] + bI;
                    float gF = acc[1][bb] + bF;
                    float gG = acc[2][bb] + bG;
                    float gO = acc[3][bb] + bO;
                    float cN = sigm(gF) * cr[bb] + sigm(gI) * tanhf(gG);
                    float hN = sigm(gO) * tanhf(cN);
                    cr[bb] = cN;
                    __hip_atomic_store(&hA[(size_t)(t + 1) * HB + unit * B_ + b],
                                       hN, __ATOMIC_RELAXED,
                                       __HIP_MEMORY_SCOPE_AGENT);
                }
            }
            __syncthreads();           // drain all lanes' h stores
            if (tid == 0) {
                asm volatile("s_waitcnt vmcnt(0) lgkmcnt(0)" ::: "memory");
                __hip_atomic_store(&flag_h[gi * 16], (unsigned)(t + 1),
                                   __ATOMIC_RELAXED, __HIP_MEMORY_SCOPE_AGENT);
            }
            // wait full h[t+1] (128 gate flags), then next partial
            wait_flags(flag_h, NGATE, (unsigned)(t + 1), &syncf[2], tid);

            #pragma unroll
            for (int j = 0; j < 4; ++j)
                #pragma unroll
                for (int bb = 0; bb < 8; ++bb) acc[j][bb] = 0.f;
            if (t + 1 < S_) {
                const float* xs2 = xT + (size_t)(t + 1) * I_ * B_;
                const float* hs2 = hA + (size_t)(t + 1) * HB;
                #pragma unroll
                for (int i = 0; i < 8; ++i) {
                    const int k = ks + (i << 5);
                    GEMM_STEP(k, xs2 + k * B_ + b0);
                }
                #pragma unroll
                for (int i = 0; i < 16; ++i) {
                    const int k = ks + (i << 5);
                    GEMM_STEP(320 + k, hs2 + k * B_ + b0);
                }
            }
        }
        return;
    }

    // ================= PB block main loop =================
    const int b = bi;
    float* Mb = Mem + (size_t)b * N_ * C_;
    for (int t = 0; t < S_; ++t) {
        wait_flags(flag_h, NGATE, (unsigned)(t + 1), &syncf[0], tid);

        const float* hs = hA + (size_t)(t + 1) * HB;
        h_lds[tid] = __hip_atomic_load(&hs[tid * B_ + b], __ATOMIC_RELAXED,
                                       __HIP_MEMORY_SCOPE_AGENT);
        __syncthreads();

        // head GEMM (fp16 weights): p = W_head @ h + b_head, 2 thr/row
        {
            const int sub  = tid & 1;
            const int row0 = tid >> 1;
            const float* hb = &h_lds[sub * 256];
            #pragma unroll
            for (int rep = 0; rep < 2; ++rep) {
                const int row = (rep == 0) ? row0
                              : ((row0 < P_ - 256) ? row0 + 256 : -1);
                if (row >= 0) {
                    const unsigned short* wrow = whH + row * H_ + sub * 256;
                    float acch = 0.f;
                    #pragma unroll 4
                    for (int k2 = 0; k2 < 256; k2 += 8) {
                        float4 raw = *(const float4*)&wrow[k2];
                        const __half2* hp = (const __half2*)&raw;
                        float2 f0 = __half22float2(hp[0]);
                        float2 f1 = __half22float2(hp[1]);
                        float2 f2 = __half22float2(hp[2]);
                        float2 f3 = __half22float2(hp[3]);
                        acch += f0.x * hb[k2]     + f0.y * hb[k2 + 1]
                              + f1.x * hb[k2 + 2] + f1.y * hb[k2 + 3]
                              + f2.x * hb[k2 + 4] + f2.y * hb[k2 + 5]
                              + f3.x * hb[k2 + 6] + f3.y * hb[k2 + 7];
                    }
                    acch += __shfl_xor(acch, 1, 64);
                    if (sub == 0) p_lds[row] = acch + bhead[row];
                }
            }
        }
        __syncthreads();

        // dual-pass addressing: grp0=read head, grp1=write head (concurrent)
        {
            float* wtmpA = h_lds;            // alias (h_lds dead)
            float* sbufA = h_lds + 256;
            const int grp = (tid >> 7) & 1;
            const int l   = tid & 127;
            const bool act256 = (tid < 256);
            const int o = grp ? 70 : 0;
            const int widx = (tid >> 6) & 1;

            float z = 0.f, gate = 0.f, s0 = 0.f, s1 = 0.f, s2 = 0.f,
                  gamma = 1.f;
            if (act256) {
                float beta = splus(p_lds[o + 64]);
                gate = sigm(p_lds[o + 65]);
                float sa = p_lds[o + 66], sbv = p_lds[o + 67],
                      sc = p_lds[o + 68];
                float sm3 = fmaxf(sa, fmaxf(sbv, sc));
                float ea = __expf(sa - sm3), eb = __expf(sbv - sm3),
                      ec = __expf(sc - sm3);
                float es3 = ea + eb + ec;
                s0 = ea / es3; s1 = eb / es3; s2 = ec / es3;
                gamma = 1.f + splus(p_lds[o + 69]);
                float kk = 0.f;
                #pragma unroll 8
                for (int c = 0; c < C_; ++c) {
                    float kv = p_lds[o + c]; kk += kv * kv;
                }
                const float knorm = sqrtf(kk) + EPSX;
                float dot = 0.f, mm = 0.f;
                #pragma unroll
                for (int c = 0; c < C_; c += 4) {
                    float4 m4 = *(const float4*)&Mb[l * C_ + c];
                    dot += m4.x * p_lds[o + c]     + m4.y * p_lds[o + c + 1]
                         + m4.z * p_lds[o + c + 2] + m4.w * p_lds[o + c + 3];
                    mm  += m4.x * m4.x + m4.y * m4.y + m4.z * m4.z
                         + m4.w * m4.w;
                }
                z = beta * (dot / ((sqrtf(mm) + EPSX) * knorm));
            }
            float zm = wave_max(z);
            if (act256 && (tid & 63) == 0) sbufA[grp * 8 + widx] = zm;
            __syncthreads();
            const float zmax = fmaxf(sbufA[grp * 8], sbufA[grp * 8 + 1]);
            float ev = act256 ? __expf(z - zmax) : 0.f;
            float es = wave_sum(ev);
            if (act256 && (tid & 63) == 0) sbufA[grp * 8 + 2 + widx] = es;
            __syncthreads();
            const float esum = sbufA[grp * 8 + 2] + sbufA[grp * 8 + 3];
            if (act256) {
                float wc = ev / esum;
                float wprev = grp ? wldsW[l] : wldsR[l];
                wtmpA[grp * 128 + l] = gate * wc + (1.f - gate) * wprev;
            }
            __syncthreads();
            float wp = 0.f;
            if (act256) {
                float wsft = s0 * wtmpA[grp * 128 + ((l + 1) & 127)]
                           + s1 * wtmpA[grp * 128 + l]
                           + s2 * wtmpA[grp * 128 + ((l - 1) & 127)];
                wp = __powf(wsft + EPSX, gamma);
            }
            float ps = wave_sum(wp);
            if (act256 && (tid & 63) == 0) sbufA[grp * 8 + 4 + widx] = ps;
            __syncthreads();
            const float psum = sbufA[grp * 8 + 4] + sbufA[grp * 8 + 5];
            if (act256) {
                float wn = wp / psum;
                if (grp) wldsW[l] = wn; else wldsR[l] = wn;
            }
            __syncthreads();
        }

        // M = M*(1 - w_w e) + w_w a
        for (int idx = tid; idx < (N_ * C_) / 4; idx += 512) {
            const int n = idx >> 4;
            const int c = (idx & 15) << 2;
            const float wwn = wldsW[n];
            float4 m4 = *(float4*)&Mb[n * C_ + c];
            m4.x = m4.x * (1.f - wwn * sigm(p_lds[140 + c]))     + wwn * p_lds[204 + c];
            m4.y = m4.y * (1.f - wwn * sigm(p_lds[140 + c + 1])) + wwn * p_lds[204 + c + 1];
            m4.z = m4.z * (1.f - wwn * sigm(p_lds[140 + c + 2])) + wwn * p_lds[204 + c + 2];
            m4.w = m4.w * (1.f - wwn * sigm(p_lds[140 + c + 3])) + wwn * p_lds[204 + c + 3];
            *(float4*)&Mb[n * C_ + c] = m4;
        }
        __syncthreads();

        // r = w_r @ M_new -> publish
        {
            const int c = tid >> 3, ns = tid & 7;
            float accr = 0.f;
            #pragma unroll
            for (int i = 0; i < 16; ++i) {
                const int n = ns + 8 * i;
                accr += wldsR[n] * Mb[n * C_ + c];
            }
            accr += __shfl_xor(accr, 4, 64);
            accr += __shfl_xor(accr, 2, 64);
            accr += __shfl_xor(accr, 1, 64);
            if (ns == 0)
                __hip_atomic_store(&rA[(size_t)(t + 1) * C_ * B_ + c * B_ + b],
                                   accr, __ATOMIC_RELAXED,
                                   __HIP_MEMORY_SCOPE_AGENT);
        }
        __syncthreads();               // drain r stores
        if (tid == 0) {
            asm volatile("s_waitcnt vmcnt(0) lgkmcnt(0)" ::: "memory");
            __hip_atomic_store(&flag_r[b * 16], (unsigned)(t + 1),
                               __ATOMIC_RELAXED, __HIP_MEMORY_SCOPE_AGENT);
        }
    }
}

// ---------------- final output GEMM ----------------
__global__ __launch_bounds__(256)
void out_kernel(const float* __restrict__ ws, const float* __restrict__ bout,
                float* __restrict__ out)
{
    __shared__ float actL[(H_ + C_) * 16];
    const float* hA  = ws + OFF_HA;
    const float* rA  = ws + OFF_RA;
    const float* WoT = ws + OFF_WOT;
    const int t   = blockIdx.x >> 1;
    const int bh  = blockIdx.x & 1;
    const int tid = threadIdx.x;

    for (int idx = tid; idx < (H_ + C_) * 16; idx += 256) {
        const int k = idx >> 4, bl2 = idx & 15, b = bh * 16 + bl2;
        float v = (k < H_) ? hA[(size_t)(t + 1) * HB + k * B_ + b]
                           : rA[(size_t)(t + 1) * C_ * B_ + (k - H_) * B_ + b];
        actL[k * 16 + bl2] = v;
    }
    __syncthreads();

    const int ot = tid & 63, bt = tid >> 6;
    const int o0 = ot * 4, bl0 = bt * 4;
    float acc[4][4] = {{0,0,0,0},{0,0,0,0},{0,0,0,0},{0,0,0,0}};
    for (int k = 0; k < H_ + C_; ++k) {
        const float4 w4 = *(const float4*)&WoT[k * O_ + o0];
        const float4 a4 = *(const float4*)&actL[k * 16 + bl0];
        const float wv[4] = {w4.x, w4.y, w4.z, w4.w};
        const float av[4] = {a4.x, a4.y, a4.z, a4.w};
        #pragma unroll
        for (int j = 0; j < 4; ++j)
            #pragma unroll
            for (int bb = 0; bb < 4; ++bb)
                acc[j][bb] += wv[j] * av[bb];
    }
    const float4 bo = *(const float4*)&bout[o0];
    #pragma unroll
    for (int bb = 0; bb < 4; ++bb) {
        const int b = bh * 16 + bl0 + bb;
        float4 res;
        res.x = acc[0][bb] + bo.x;
        res.y = acc[1][bb] + bo.y;
        res.z = acc[2][bb] + bo.z;
        res.w = acc[3][bb] + bo.w;
        *(float4*)&out[((size_t)b * S_ + t) * O_ + o0] = res;
    }
}

extern "C" void kernel_launch(void* const* d_in, const int* in_sizes, int n_in,
                              void* d_out, int out_size, void* d_ws, size_t ws_size,
                              hipStream_t stream)
{
    const float* x    = (const float*)d_in[0];
    const float* Wih  = (const float*)d_in[1];
    const float* Whh  = (const float*)d_in[2];
    const float* bl   = (const float*)d_in[3];
    const float* Whd  = (const float*)d_in[4];
    const float* bhd  = (const float*)d_in[5];
    const float* Wout = (const float*)d_in[6];
    const float* bout = (const float*)d_in[7];
    float* ws  = (float*)d_ws;
    float* out = (float*)d_out;

    prep_kernel<<<10529, 256, 0, stream>>>(x, Wout, Whd, ws);

    void* args[] = { (void*)&Wih, (void*)&Whh, (void*)&bl,
                     (void*)&bhd, (void*)&ws };
    (void)hipLaunchCooperativeKernel((void*)ntm_loop, dim3(NBLK), dim3(512), args, 0, stream);

    out_kernel<<<512, 256, 0, stream>>>(ws, bout, out);
}